// Round 1
// baseline (1403.774 us; speedup 1.0000x reference)
//
#include <hip/hip_runtime.h>

#define EDGES 800000
#define NODES 50000
#define NSLOT 4
#define HIDN  64

__device__ __forceinline__ float silu_f(float t) {
    return t * (1.0f / (1.0f + __expf(-t)));
}

// Detect edge_index storage: if the first 2048 elements' high 32-bit words
// (int64 interpretation) are ALL zero -> int64 layout; else int32.
// Writes flag: 1 = int32 layout, 0 = int64 layout.
__global__ void detect_idx_kernel(const int* __restrict__ ei, int* __restrict__ flag) {
    int t = threadIdx.x;
    int v = 0;
    for (int k = t; k < 2048; k += 64) v |= ei[2 * k + 1];
    unsigned long long m = __ballot(v != 0);
    if (t == 0) flag[0] = (m != 0ull) ? 1 : 0;
}

__global__ __launch_bounds__(256, 2) void gnn_edge_kernel(
    const float* __restrict__ x, const float* __restrict__ theta,
    const float* __restrict__ H, const int* __restrict__ ei,
    const float* __restrict__ W1, const float* __restrict__ b1,
    const float* __restrict__ W2, const float* __restrict__ b2,
    const float* __restrict__ W3, const float* __restrict__ b3,
    float* __restrict__ out, const int* __restrict__ flag)
{
    int e = blockIdx.x * blockDim.x + threadIdx.x;
    if (e >= EDGES) return;

    bool idx32 = (flag == nullptr) || (flag[0] != 0);
    int i, j;
    if (idx32) { i = ei[e];     j = ei[EDGES + e]; }
    else       { i = ei[2 * e]; j = ei[2 * EDGES + 2 * e]; }

    float xi0 = x[3 * i + 0], xi1 = x[3 * i + 1], xi2 = x[3 * i + 2];
    float xj0 = x[3 * j + 0], xj1 = x[3 * j + 1], xj2 = x[3 * j + 2];
    float dx0 = xj0 - xi0, dx1 = xj1 - xi1, dz = xj2 - xi2;

    float rxy2 = dx0 * dx0 + dx1 * dx1;
    float r3d  = sqrtf(rxy2 + dz * dz);
    float rxy  = sqrtf(rxy2);
    float phi  = atan2f(dx1, dx0);
    float ti   = theta[i], tj = theta[j];
    float dphi = phi - ti;
    float sdp, cdp;
    sincosf(dphi, &sdp, &cdp);
    float dt2 = 2.0f * (tj - ti);
    float s2, c2;
    sincosf(dt2, &s2, &c2);
    float sg = (dz > 0.0f) ? 1.0f : ((dz < 0.0f) ? -1.0f : 0.0f);

    float g0 = r3d, g1 = rxy, g2 = dz, g3 = sdp, g4 = cdp, g5 = s2, g6 = c2, g7 = sg * s2;

    for (int s = 0; s < NSLOT; ++s) {
        float vx = H[((long)j * NSLOT + s) * 2 + 0];
        float vy = H[((long)j * NSLOT + s) * 2 + 1];
        float in0 = c2 * vx - s2 * vy;
        float in1 = s2 * vx + c2 * vy;
        float in[10] = {in0, in1, g0, g1, g2, g3, g4, g5, g6, g7};

        float h1[HIDN];
        #pragma unroll
        for (int h = 0; h < HIDN; ++h) h1[h] = b1[h];
        #pragma unroll
        for (int d = 0; d < 10; ++d) {
            float v = in[d];
            #pragma unroll
            for (int h = 0; h < HIDN; ++h) h1[h] = fmaf(v, W1[d * HIDN + h], h1[h]);
        }
        #pragma unroll
        for (int h = 0; h < HIDN; ++h) h1[h] = silu_f(h1[h]);

        float h2[HIDN];
        #pragma unroll
        for (int k = 0; k < HIDN; ++k) h2[k] = b2[k];
        #pragma unroll
        for (int k = 0; k < HIDN; ++k) {
            float v = h1[k];
            #pragma unroll
            for (int jj = 0; jj < HIDN; ++jj) h2[jj] = fmaf(v, W2[k * HIDN + jj], h2[jj]);
        }

        float m0 = b3[0], m1 = b3[1];
        #pragma unroll
        for (int k = 0; k < HIDN; ++k) {
            float t = silu_f(h2[k]);
            m0 = fmaf(t, W3[2 * k + 0], m0);
            m1 = fmaf(t, W3[2 * k + 1], m1);
        }

        atomicAdd(&out[((long)i * NSLOT + s) * 2 + 0], m0);
        atomicAdd(&out[((long)i * NSLOT + s) * 2 + 1], m1);
    }
}

extern "C" void kernel_launch(void* const* d_in, const int* in_sizes, int n_in,
                              void* d_out, int out_size, void* d_ws, size_t ws_size,
                              hipStream_t stream) {
    const float* x     = (const float*)d_in[0];
    const float* theta = (const float*)d_in[1];
    const float* H     = (const float*)d_in[2];
    const int*   ei    = (const int*)d_in[3];
    const float* W1    = (const float*)d_in[4];
    const float* b1    = (const float*)d_in[5];
    const float* W2    = (const float*)d_in[6];
    const float* b2    = (const float*)d_in[7];
    const float* W3    = (const float*)d_in[8];
    const float* b3    = (const float*)d_in[9];
    float* out = (float*)d_out;

    hipMemsetAsync(d_out, 0, (size_t)out_size * sizeof(float), stream);

    int* flag = nullptr;
    if (ws_size >= sizeof(int)) {
        flag = (int*)d_ws;
        detect_idx_kernel<<<1, 64, 0, stream>>>(ei, flag);
    }

    int grid = (EDGES + 255) / 256;
    gnn_edge_kernel<<<grid, 256, 0, stream>>>(x, theta, H, ei,
                                              W1, b1, W2, b2, W3, b3,
                                              out, flag);
}

// Round 2
// 248.319 us; speedup vs baseline: 5.6531x; 5.6531x over previous
//
#include <hip/hip_runtime.h>

#define EDGES 800000
#define GROUPS 10           // edge-groups per block
#define EPB (GROUPS * 64)   // edges per block = 640; 1250 blocks exactly

typedef __attribute__((ext_vector_type(8))) short short8;
typedef __attribute__((ext_vector_type(4))) float f32x4;

__device__ __forceinline__ unsigned short f2bf(float f) {
    union { float f; unsigned u; } c; c.f = f;
    return (unsigned short)((c.u + 0x7FFFu + ((c.u >> 16) & 1u)) >> 16);
}
__device__ __forceinline__ float silu_f(float t) {
    return t / (1.0f + __expf(-t));
}

// flag: 1 = int32 edge_index layout, 0 = int64 (low words at even positions)
__global__ void detect_idx_kernel(const int* __restrict__ ei, int* __restrict__ flag) {
    int t = threadIdx.x;
    int v = 0;
    for (int k = t; k < 2048; k += 64) v |= ei[2 * k + 1];
    unsigned long long m = __ballot(v != 0);
    if (t == 0) flag[0] = (m != 0ull) ? 1 : 0;
}

__global__ __launch_bounds__(256, 2) void gnn_mfma_kernel(
    const float* __restrict__ x, const float* __restrict__ theta,
    const float* __restrict__ H, const int* __restrict__ ei,
    const float* __restrict__ W1, const float* __restrict__ b1,
    const float* __restrict__ W2, const float* __restrict__ b2,
    const float* __restrict__ W3, const float* __restrict__ b3,
    float* __restrict__ out, const int* __restrict__ flag)
{
    __shared__ unsigned short Xs[256 * 32];  // 16 KB: 256 rows x 32 bf16, chunk-swizzled
    __shared__ int idxs[256];                // out base per row

    const int t    = threadIdx.x;
    const int lane = t & 63;
    const int wv   = t >> 6;
    const int g16  = lane >> 4;   // k-chunk group of this lane
    const int l15  = lane & 15;
    const bool idx32 = (flag[0] != 0);

    // ---------- weight fragments (loaded once per thread) ----------
    // Layer 1 (swapped): A = W1^T tile nt: row = h1 = 16*nt + l15, k = 8*g16+j
    //   k<10 -> W1[k][h], k==10 -> b1[h] (bias via constant-1 feature), else 0
    short8 w1f[4];
    #pragma unroll
    for (int nt = 0; nt < 4; ++nt) {
        short8 v;
        #pragma unroll
        for (int j = 0; j < 8; ++j) {
            int k = 8 * g16 + j;
            int h = nt * 16 + l15;
            float w = 0.0f;
            if (k < 10)      w = W1[k * 64 + h];
            else if (k == 10) w = b1[h];
            v[j] = (short)f2bf(w);
        }
        w1f[nt] = v;
    }
    // Hidden-permutation: physical k-slot p = 32s + 8g + j holds logical unit
    //   lambda(p) = 16*(2s + (j>>2)) + 4g + (j&3)   (matches C^T->B repack below)
    short8 w2f[4][2];
    #pragma unroll
    for (int mt = 0; mt < 4; ++mt) {
        #pragma unroll
        for (int s = 0; s < 2; ++s) {
            short8 v;
            #pragma unroll
            for (int j = 0; j < 8; ++j) {
                int h1 = 16 * (2 * s + (j >> 2)) + 4 * g16 + (j & 3);
                int h2 = 16 * mt + l15;
                v[j] = (short)f2bf(W2[h1 * 64 + h2]);
            }
            w2f[mt][s] = v;
        }
    }
    short8 w3f[2];
    #pragma unroll
    for (int s = 0; s < 2; ++s) {
        short8 v;
        #pragma unroll
        for (int j = 0; j < 8; ++j) {
            int h2 = 16 * (2 * s + (j >> 2)) + 4 * g16 + (j & 3);
            float w = (l15 < 2) ? W3[h2 * 2 + l15] : 0.0f;
            v[j] = (short)f2bf(w);
        }
        w3f[s] = v;
    }
    f32x4 bias2[4];
    #pragma unroll
    for (int mt = 0; mt < 4; ++mt) {
        #pragma unroll
        for (int r = 0; r < 4; ++r)
            bias2[mt][r] = b2[16 * mt + 4 * g16 + r];
    }
    f32x4 c3i;
    #pragma unroll
    for (int r = 0; r < 4; ++r) {
        int o = 4 * g16 + r;
        c3i[r] = (o == 0) ? b3[0] : ((o == 1) ? b3[1] : 0.0f);
    }

    for (int grp = 0; grp < GROUPS; ++grp) {
        const int e0 = blockIdx.x * EPB + grp * 64;

        // ---------- phase 1: geometry, one (edge,slot) row per thread ----------
        {
            int el = t >> 2, slot = t & 3;
            int e = e0 + el;
            int i, j;
            if (idx32) { i = ei[e];     j = ei[EDGES + e]; }
            else       { i = ei[2 * e]; j = ei[2 * EDGES + 2 * e]; }

            float dx0 = x[3 * j + 0] - x[3 * i + 0];
            float dx1 = x[3 * j + 1] - x[3 * i + 1];
            float dz  = x[3 * j + 2] - x[3 * i + 2];
            float rxy2 = dx0 * dx0 + dx1 * dx1;
            float r3d  = sqrtf(rxy2 + dz * dz);
            float rxy  = sqrtf(rxy2);
            float phi  = atan2f(dx1, dx0);
            float ti = theta[i], tj = theta[j];
            float sdp, cdp; sincosf(phi - ti, &sdp, &cdp);
            float s2,  c2;  sincosf(2.0f * (tj - ti), &s2, &c2);
            float sg = (dz > 0.0f) ? 1.0f : ((dz < 0.0f) ? -1.0f : 0.0f);
            float vx = H[((long)j * 4 + slot) * 2 + 0];
            float vy = H[((long)j * 4 + slot) * 2 + 1];
            float in0 = c2 * vx - s2 * vy;
            float in1 = s2 * vx + c2 * vy;

            short8 cA, cB, zz;
            cA[0] = (short)f2bf(in0); cA[1] = (short)f2bf(in1);
            cA[2] = (short)f2bf(r3d); cA[3] = (short)f2bf(rxy);
            cA[4] = (short)f2bf(dz);  cA[5] = (short)f2bf(sdp);
            cA[6] = (short)f2bf(cdp); cA[7] = (short)f2bf(s2);
            cB[0] = (short)f2bf(c2);  cB[1] = (short)f2bf(sg * s2);
            cB[2] = (short)0x3F80;    // bias feature = 1.0
            cB[3] = 0; cB[4] = 0; cB[5] = 0; cB[6] = 0; cB[7] = 0;
            #pragma unroll
            for (int q = 0; q < 8; ++q) zz[q] = 0;

            int row = t;
            unsigned short* bp = &Xs[row * 32];
            int sw = row & 3;  // chunk XOR swizzle (bank-conflict reduction)
            *(short8*)(bp + ((0 ^ sw) << 3)) = cA;
            *(short8*)(bp + ((1 ^ sw) << 3)) = cB;
            *(short8*)(bp + ((2 ^ sw) << 3)) = zz;
            *(short8*)(bp + ((3 ^ sw) << 3)) = zz;
            idxs[row] = i * 8 + slot * 2;
        }
        __syncthreads();

        // ---------- phase 2: 4 M-tiles of 16 edge-rows per wave ----------
        #pragma unroll
        for (int tt = 0; tt < 4; ++tt) {
            int row = wv * 64 + tt * 16 + l15;
            // B-frag of X^T: col = edge-row = l15, k = 8*g16+j (swizzled chunk)
            short8 xb = *(const short8*)(&Xs[row * 32] + ((g16 ^ (row & 3)) << 3));

            f32x4 z4 = {0.0f, 0.0f, 0.0f, 0.0f};
            f32x4 c1[4];
            #pragma unroll
            for (int nt = 0; nt < 4; ++nt)
                c1[nt] = __builtin_amdgcn_mfma_f32_16x16x32_bf16(w1f[nt], xb, z4, 0, 0, 0);

            short8 pb[2];
            #pragma unroll
            for (int s = 0; s < 2; ++s) {
                short8 v;
                #pragma unroll
                for (int j = 0; j < 8; ++j)
                    v[j] = (short)f2bf(silu_f(c1[2 * s + (j >> 2)][j & 3]));
                pb[s] = v;
            }

            f32x4 c2a[4];
            #pragma unroll
            for (int mt = 0; mt < 4; ++mt) {
                f32x4 acc = __builtin_amdgcn_mfma_f32_16x16x32_bf16(w2f[mt][0], pb[0], bias2[mt], 0, 0, 0);
                acc       = __builtin_amdgcn_mfma_f32_16x16x32_bf16(w2f[mt][1], pb[1], acc,       0, 0, 0);
                c2a[mt] = acc;
            }

            short8 qb[2];
            #pragma unroll
            for (int s = 0; s < 2; ++s) {
                short8 v;
                #pragma unroll
                for (int j = 0; j < 8; ++j)
                    v[j] = (short)f2bf(silu_f(c2a[2 * s + (j >> 2)][j & 3]));
                qb[s] = v;
            }

            f32x4 c3 = __builtin_amdgcn_mfma_f32_16x16x32_bf16(w3f[0], qb[0], c3i, 0, 0, 0);
            c3       = __builtin_amdgcn_mfma_f32_16x16x32_bf16(w3f[1], qb[1], c3,  0, 0, 0);

            // C3^T: lane l15 holds edge-row, regs 0/1 (g16==0) = channels 0/1
            if (g16 == 0) {
                int ob = idxs[row];
                atomicAdd(&out[ob + 0], c3[0]);
                atomicAdd(&out[ob + 1], c3[1]);
            }
        }
        __syncthreads();
    }
}

extern "C" void kernel_launch(void* const* d_in, const int* in_sizes, int n_in,
                              void* d_out, int out_size, void* d_ws, size_t ws_size,
                              hipStream_t stream) {
    const float* x     = (const float*)d_in[0];
    const float* theta = (const float*)d_in[1];
    const float* H     = (const float*)d_in[2];
    const int*   ei    = (const int*)d_in[3];
    const float* W1    = (const float*)d_in[4];
    const float* b1    = (const float*)d_in[5];
    const float* W2    = (const float*)d_in[6];
    const float* b2    = (const float*)d_in[7];
    const float* W3    = (const float*)d_in[8];
    const float* b3    = (const float*)d_in[9];
    float* out = (float*)d_out;

    hipMemsetAsync(d_out, 0, (size_t)out_size * sizeof(float), stream);

    int* flag = (int*)d_ws;
    detect_idx_kernel<<<1, 64, 0, stream>>>(ei, flag);

    gnn_mfma_kernel<<<EDGES / EPB, 256, 0, stream>>>(x, theta, H, ei,
                                                     W1, b1, W2, b2, W3, b3,
                                                     out, flag);
}

// Round 3
// 129.983 us; speedup vs baseline: 10.7997x; 1.9104x over previous
//
#include <hip/hip_runtime.h>

#define EDGES 800000
#define GROUPS 10           // edge-groups per block
#define EPB (GROUPS * 64)   // edges per block = 640; 1250 blocks exactly

typedef __attribute__((ext_vector_type(8))) short short8;
typedef __attribute__((ext_vector_type(4))) float f32x4;

__device__ __forceinline__ unsigned short f2bf(float f) {   // cold path (weights)
    union { float f; unsigned u; } c; c.f = f;
    return (unsigned short)((c.u + 0x7FFFu + ((c.u >> 16) & 1u)) >> 16);
}

// packed bf16 pair: one v_cvt_pk_bf16_f32 -> u32 word {lo, hi}
__device__ __forceinline__ unsigned pk2(float lo, float hi) {
    unsigned r;
    asm("v_cvt_pk_bf16_f32 %0, %1, %2" : "=v"(r) : "v"(lo), "v"(hi));
    return r;
}

__device__ __forceinline__ float silu_f(float t) {
    // t * rcp(1+exp(-t)): v_rcp instead of precise fp32 divide (~9 instr saved)
    return t * __builtin_amdgcn_rcpf(1.0f + __expf(-t));
}

// fast atan2: A&S 4.4.49 poly, |err| <= ~1e-5; atan2(0,0) -> 0 like numpy
__device__ __forceinline__ float fast_atan2f(float y, float x) {
    float ax = __builtin_fabsf(x), ay = __builtin_fabsf(y);
    float mx = fmaxf(ax, ay), mn = fminf(ax, ay);
    float z  = mn * __builtin_amdgcn_rcpf(mx);
    float z2 = z * z;
    float p  = fmaf(z2, 0.0208351f, -0.0851330f);
    p = fmaf(z2, p, 0.1801410f);
    p = fmaf(z2, p, -0.3302995f);
    p = fmaf(z2, p, 0.9998660f);
    float t = z * p;
    t = (ay > ax)   ? 1.57079632679f - t : t;
    t = (x < 0.0f)  ? 3.14159265359f - t : t;
    t = (y < 0.0f)  ? -t : t;
    return (mx > 0.0f) ? t : 0.0f;
}

// flag: 1 = int32 edge_index layout, 0 = int64 (low words at even positions)
__global__ void detect_idx_kernel(const int* __restrict__ ei, int* __restrict__ flag) {
    int t = threadIdx.x;
    int v = 0;
    for (int k = t; k < 2048; k += 64) v |= ei[2 * k + 1];
    unsigned long long m = __ballot(v != 0);
    if (t == 0) flag[0] = (m != 0ull) ? 1 : 0;
}

__global__ __launch_bounds__(256, 2) void gnn_mfma_kernel(
    const float* __restrict__ x, const float* __restrict__ theta,
    const float* __restrict__ H, const int* __restrict__ ei,
    const float* __restrict__ W1, const float* __restrict__ b1,
    const float* __restrict__ W2, const float* __restrict__ b2,
    const float* __restrict__ W3, const float* __restrict__ b3,
    float* __restrict__ out, const int* __restrict__ flag)
{
    __shared__ unsigned short Xs[256 * 32];  // 16 KB: 256 rows x 32 bf16, chunk-swizzled
    __shared__ int idxs[256];                // out base per row

    const int t    = threadIdx.x;
    const int lane = t & 63;
    const int wv   = t >> 6;
    const int g16  = lane >> 4;
    const int l15  = lane & 15;
    const bool idx32 = (flag[0] != 0);

    // ---------- weight fragments (cold, once per block) ----------
    short8 w1f[4];
    #pragma unroll
    for (int nt = 0; nt < 4; ++nt) {
        short8 v;
        #pragma unroll
        for (int j = 0; j < 8; ++j) {
            int k = 8 * g16 + j;
            int h = nt * 16 + l15;
            float w = 0.0f;
            if (k < 10)       w = W1[k * 64 + h];
            else if (k == 10) w = b1[h];
            v[j] = (short)f2bf(w);
        }
        w1f[nt] = v;
    }
    // physical k-slot p = 32s + 8g + j holds logical unit
    //   lambda(p) = 16*(2s + (j>>2)) + 4g + (j&3)
    short8 w2f[4][2];
    #pragma unroll
    for (int mt = 0; mt < 4; ++mt) {
        #pragma unroll
        for (int s = 0; s < 2; ++s) {
            short8 v;
            #pragma unroll
            for (int j = 0; j < 8; ++j) {
                int h1 = 16 * (2 * s + (j >> 2)) + 4 * g16 + (j & 3);
                int h2 = 16 * mt + l15;
                v[j] = (short)f2bf(W2[h1 * 64 + h2]);
            }
            w2f[mt][s] = v;
        }
    }
    short8 w3f[2];
    #pragma unroll
    for (int s = 0; s < 2; ++s) {
        short8 v;
        #pragma unroll
        for (int j = 0; j < 8; ++j) {
            int h2 = 16 * (2 * s + (j >> 2)) + 4 * g16 + (j & 3);
            float w = (l15 < 2) ? W3[h2 * 2 + l15] : 0.0f;
            v[j] = (short)f2bf(w);
        }
        w3f[s] = v;
    }
    f32x4 bias2[4];
    #pragma unroll
    for (int mt = 0; mt < 4; ++mt) {
        #pragma unroll
        for (int r = 0; r < 4; ++r)
            bias2[mt][r] = b2[16 * mt + 4 * g16 + r];
    }
    f32x4 c3i;
    #pragma unroll
    for (int r = 0; r < 4; ++r) {
        int o = 4 * g16 + r;
        c3i[r] = (o == 0) ? b3[0] : ((o == 1) ? b3[1] : 0.0f);
    }

    for (int grp = 0; grp < GROUPS; ++grp) {
        const int e0 = blockIdx.x * EPB + grp * 64;

        // ---------- phase 1: geometry, one (edge,slot) row per thread ----------
        {
            int el = t >> 2, slot = t & 3;
            int e = e0 + el;
            int i, j;
            if (idx32) { i = ei[e];     j = ei[EDGES + e]; }
            else       { i = ei[2 * e]; j = ei[2 * EDGES + 2 * e]; }

            float dx0 = x[3 * j + 0] - x[3 * i + 0];
            float dx1 = x[3 * j + 1] - x[3 * i + 1];
            float dz  = x[3 * j + 2] - x[3 * i + 2];
            float rxy2 = dx0 * dx0 + dx1 * dx1;
            float r3d  = __builtin_amdgcn_sqrtf(rxy2 + dz * dz);
            float rxy  = __builtin_amdgcn_sqrtf(rxy2);
            float phi  = fast_atan2f(dx1, dx0);
            float ti = theta[i], tj = theta[j];
            float dphi = phi - ti;
            float sdp = __sinf(dphi), cdp = __cosf(dphi);
            float dt2 = 2.0f * (tj - ti);
            float s2 = __sinf(dt2), c2 = __cosf(dt2);
            float g7 = (dz > 0.0f) ? s2 : ((dz < 0.0f) ? -s2 : 0.0f);

            float2 hv = *(const float2*)&H[((long)j * 4 + slot) * 2];
            float in0 = c2 * hv.x - s2 * hv.y;
            float in1 = s2 * hv.x + c2 * hv.y;

            union { short8 s8; unsigned u[4]; } A, B;
            A.u[0] = pk2(in0, in1);
            A.u[1] = pk2(r3d, rxy);
            A.u[2] = pk2(dz, sdp);
            A.u[3] = pk2(cdp, s2);
            B.u[0] = pk2(c2, g7);
            B.u[1] = 0x00003F80u;   // {1.0bf, 0}
            B.u[2] = 0; B.u[3] = 0;
            short8 zz;
            #pragma unroll
            for (int q = 0; q < 8; ++q) zz[q] = 0;

            int row = t;
            unsigned short* bp = &Xs[row * 32];
            int sw = row & 3;  // chunk XOR swizzle
            *(short8*)(bp + ((0 ^ sw) << 3)) = A.s8;
            *(short8*)(bp + ((1 ^ sw) << 3)) = B.s8;
            *(short8*)(bp + ((2 ^ sw) << 3)) = zz;
            *(short8*)(bp + ((3 ^ sw) << 3)) = zz;
            idxs[row] = i * 8 + slot * 2;
        }
        __syncthreads();

        // ---------- phase 2: 4 M-tiles of 16 edge-rows per wave ----------
        #pragma unroll
        for (int tt = 0; tt < 4; ++tt) {
            int row = wv * 64 + tt * 16 + l15;
            short8 xb = *(const short8*)(&Xs[row * 32] + ((g16 ^ (row & 3)) << 3));

            f32x4 z4 = {0.0f, 0.0f, 0.0f, 0.0f};
            f32x4 c1[4];
            #pragma unroll
            for (int nt = 0; nt < 4; ++nt)
                c1[nt] = __builtin_amdgcn_mfma_f32_16x16x32_bf16(w1f[nt], xb, z4, 0, 0, 0);

            // pack word w of pb[s]: elements j=2w,2w+1 -> c1[2s+(w>>1)][(w&1)*2 + {0,1}]
            short8 pb[2];
            #pragma unroll
            for (int s = 0; s < 2; ++s) {
                union { short8 s8; unsigned u[4]; } P;
                #pragma unroll
                for (int w = 0; w < 4; ++w) {
                    float lo = silu_f(c1[2 * s + (w >> 1)][(w & 1) * 2 + 0]);
                    float hi = silu_f(c1[2 * s + (w >> 1)][(w & 1) * 2 + 1]);
                    P.u[w] = pk2(lo, hi);
                }
                pb[s] = P.s8;
            }

            f32x4 c2a[4];
            #pragma unroll
            for (int mt = 0; mt < 4; ++mt) {
                f32x4 acc = __builtin_amdgcn_mfma_f32_16x16x32_bf16(w2f[mt][0], pb[0], bias2[mt], 0, 0, 0);
                acc       = __builtin_amdgcn_mfma_f32_16x16x32_bf16(w2f[mt][1], pb[1], acc,       0, 0, 0);
                c2a[mt] = acc;
            }

            short8 qb[2];
            #pragma unroll
            for (int s = 0; s < 2; ++s) {
                union { short8 s8; unsigned u[4]; } Q;
                #pragma unroll
                for (int w = 0; w < 4; ++w) {
                    float lo = silu_f(c2a[2 * s + (w >> 1)][(w & 1) * 2 + 0]);
                    float hi = silu_f(c2a[2 * s + (w >> 1)][(w & 1) * 2 + 1]);
                    Q.u[w] = pk2(lo, hi);
                }
                qb[s] = Q.s8;
            }

            f32x4 c3 = __builtin_amdgcn_mfma_f32_16x16x32_bf16(w3f[0], qb[0], c3i, 0, 0, 0);
            c3       = __builtin_amdgcn_mfma_f32_16x16x32_bf16(w3f[1], qb[1], c3,  0, 0, 0);

            if (g16 == 0) {
                int ob = idxs[row];
                atomicAdd(&out[ob + 0], c3[0]);
                atomicAdd(&out[ob + 1], c3[1]);
            }
        }
        __syncthreads();
    }
}

extern "C" void kernel_launch(void* const* d_in, const int* in_sizes, int n_in,
                              void* d_out, int out_size, void* d_ws, size_t ws_size,
                              hipStream_t stream) {
    const float* x     = (const float*)d_in[0];
    const float* theta = (const float*)d_in[1];
    const float* H     = (const float*)d_in[2];
    const int*   ei    = (const int*)d_in[3];
    const float* W1    = (const float*)d_in[4];
    const float* b1    = (const float*)d_in[5];
    const float* W2    = (const float*)d_in[6];
    const float* b2    = (const float*)d_in[7];
    const float* W3    = (const float*)d_in[8];
    const float* b3    = (const float*)d_in[9];
    float* out = (float*)d_out;

    hipMemsetAsync(d_out, 0, (size_t)out_size * sizeof(float), stream);

    int* flag = (int*)d_ws;
    detect_idx_kernel<<<1, 64, 0, stream>>>(ei, flag);

    gnn_mfma_kernel<<<EDGES / EPB, 256, 0, stream>>>(x, theta, H, ei,
                                                     W1, b1, W2, b2, W3, b3,
                                                     out, flag);
}